// Round 2
// baseline (14.639 us; speedup 1.0000x reference)
//
#include <hip/hip_runtime.h>

#define FEAT_DIM 2048
#define BATCH 1024
#define CLAMP_MIN 1e-12f
#define CLAMP_MAX 1e12f

#define ROWS_PER_BLOCK 4   // one wave per row
#define NBLOCKS (BATCH / ROWS_PER_BLOCK)  // 256

// One wave (64 lanes) per batch row: each lane loads 8 float4 of x and 8 of
// the gathered center row (16 independent dwordx4 loads in flight), computes
// sum((x-c)^2), wave-shuffle reduces, then the block combines its 4 row
// distances (clamped) and does a single atomicAdd into out[0].
__global__ void __launch_bounds__(256) center_loss_fused_kernel(
    const float* __restrict__ x,
    const int* __restrict__ labels,
    const float* __restrict__ centers,
    float* __restrict__ out) {
    const int t = threadIdx.x;
    const int wid = t >> 6;      // wave id in block: 0..3
    const int lane = t & 63;
    const int row = blockIdx.x * ROWS_PER_BLOCK + wid;

    const float4* xr = reinterpret_cast<const float4*>(x + (size_t)row * FEAT_DIM);
    const int lab = labels[row];
    const float4* cr = reinterpret_cast<const float4*>(centers + (size_t)lab * FEAT_DIM);

    // FEAT_DIM/4 = 512 float4 per row; 64 lanes -> 8 per lane
    float a0 = 0.0f, a1 = 0.0f;
#pragma unroll
    for (int i = 0; i < FEAT_DIM / 4 / 64; i += 2) {
        const float4 xv0 = xr[lane + i * 64];
        const float4 cv0 = cr[lane + i * 64];
        const float4 xv1 = xr[lane + (i + 1) * 64];
        const float4 cv1 = cr[lane + (i + 1) * 64];
        const float d0x = xv0.x - cv0.x, d0y = xv0.y - cv0.y;
        const float d0z = xv0.z - cv0.z, d0w = xv0.w - cv0.w;
        const float d1x = xv1.x - cv1.x, d1y = xv1.y - cv1.y;
        const float d1z = xv1.z - cv1.z, d1w = xv1.w - cv1.w;
        a0 += d0x * d0x + d0y * d0y + d0z * d0z + d0w * d0w;
        a1 += d1x * d1x + d1y * d1y + d1z * d1z + d1w * d1w;
    }
    float acc = a0 + a1;

    // wave-64 shuffle reduction
#pragma unroll
    for (int off = 32; off > 0; off >>= 1)
        acc += __shfl_down(acc, off, 64);

    __shared__ float wave_sums[ROWS_PER_BLOCK];
    if (lane == 0) wave_sums[wid] = acc;
    __syncthreads();
    if (t == 0) {
        float block_sum = 0.0f;
#pragma unroll
        for (int w = 0; w < ROWS_PER_BLOCK; ++w) {
            float d = wave_sums[w] * (1.0f / (float)FEAT_DIM);
            d = fminf(fmaxf(d, CLAMP_MIN), CLAMP_MAX);
            block_sum += d;
        }
        atomicAdd(out, block_sum * (1.0f / (float)BATCH));
    }
}

extern "C" void kernel_launch(void* const* d_in, const int* in_sizes, int n_in,
                              void* d_out, int out_size, void* d_ws, size_t ws_size,
                              hipStream_t stream) {
    const float* x = (const float*)d_in[0];
    const int* labels = (const int*)d_in[1];
    const float* centers = (const float*)d_in[2];
    float* out = (float*)d_out;

    hipMemsetAsync(out, 0, sizeof(float), stream);
    center_loss_fused_kernel<<<NBLOCKS, 256, 0, stream>>>(x, labels, centers, out);
}